// Round 5
// baseline (148.039 us; speedup 1.0000x reference)
//
#include <hip/hip_runtime.h>
#include <hip/hip_bf16.h>

// Embedding gather: out[tok, :] = w[ids[tok], :]
// ids: 8*2048 = 16384 int32 tokens; w: 50257 x 512 fp32; out: 16384 x 512 fp32.
// One 16B vector per thread-iteration; 128 per row.
// - grid-stride @2048 blocks (less dispatch overhead than 8192 tiny blocks)
// - row id hoisted to SGPR via readfirstlane (tok is wave-uniform: i>>7)
// - non-temporal stores via clang ext_vector (HIP float4 struct is rejected
//   by __builtin_nontemporal_store): out is write-once, keep L2 for w rows

#define TOKENS (8 * 2048)
#define UNITS 512
#define VEC_PER_ROW (UNITS / 4)  // 128 x 16B per row
#define TOTAL_VEC (TOKENS * VEC_PER_ROW)  // 2,097,152

typedef float floatx4 __attribute__((ext_vector_type(4)));

__global__ __launch_bounds__(256) void embed_gather_kernel(
    const int* __restrict__ ids,
    const floatx4* __restrict__ w,
    floatx4* __restrict__ out) {
    const int stride = gridDim.x * blockDim.x;
    for (int i = blockIdx.x * blockDim.x + threadIdx.x; i < TOTAL_VEC; i += stride) {
        const int tok  = i >> 7;   // wave-uniform: 64 consecutive lanes share tok
        const int elem = i & 127;
        // Hoist the (wave-uniform) id load to a scalar register: removes the
        // 64x-redundant per-lane VMEM load of the same 4 bytes.
        const int row = __builtin_amdgcn_readfirstlane(ids[tok]);
        const floatx4 v = w[(long)row * VEC_PER_ROW + elem];
        __builtin_nontemporal_store(v, &out[i]);
    }
}

extern "C" void kernel_launch(void* const* d_in, const int* in_sizes, int n_in,
                              void* d_out, int out_size, void* d_ws, size_t ws_size,
                              hipStream_t stream) {
    const int* ids = (const int*)d_in[0];
    const floatx4* w = (const floatx4*)d_in[1];
    floatx4* out = (floatx4*)d_out;

    const int block = 256;
    const int grid = 2048;  // grid-stride covers TOTAL_VEC
    embed_gather_kernel<<<grid, block, 0, stream>>>(ids, w, out);
}